// Round 3
// baseline (497.378 us; speedup 1.0000x reference)
//
#include <hip/hip_runtime.h>

// =====================================================================
// GraphAutoEncoder forward (all fp32). GCN via CSR build + gather.
// R9: node tile 64 -> more blocks. R10: reg double-buffer staging.
// R11: GEMMs were LDS-PIPE-bound, not latency-bound: per k, 3 ds_read
// per 32 FMA = 36 LDS cyc vs 64 VALU cyc/SIMD; 4 SIMDs share 1 LDS
// pipe -> VALUBusy capped at ~44% (measured 42%). Fix: fatter register
// tiles. TN=8xTM=8 (MT=128) / TN=4xTM=8 (MT=64): 64 FMA per 4 reads
// -> LDS at 75% of capacity when VALU full. NT=128, KC=32 (half the
// barriers). Occupancy counter WILL drop (391 blocks) - irrelevant,
// bottleneck is per-CU pipe throughput.
// R12: identical resubmit — R11 bench died to container infra (no
// pytest verdict); source re-audited for OOB/hang/alignment: clean.
// =====================================================================

constexpr int NBLK = 128;           // scatter blocks (chunk = E/128)
constexpr int GRP  = NBLK / 8;      // block-groups per XCD residue

// ---------------- GEMM: C[:,foff:foff+MT] = act(A @ W^T + b) ---------
// node tile = 128, KC=32, MT per blockIdx.y. 256 thr = (128/TN)*(MT/TM)
template <int K, int MT, int M, int ACT, bool BIAS, int TN, int TM>
__global__ __launch_bounds__(256) void gemm_rt(const float* __restrict__ A,
                                               const float* __restrict__ W,
                                               const float* __restrict__ bias,
                                               float* __restrict__ C, int N) {
    constexpr int KC  = 32;
    constexpr int NT  = 128;
    constexpr int NG  = NT / TN;                 // node groups
    constexpr int FG  = MT / TM;                 // feature groups
    static_assert(NG * FG == 256, "bad tile");
    constexpr int ALD = (NT * KC) / (4 * 256);   // float4 A-loads/thread = 4
    constexpr int WLD = (MT * KC) / (4 * 256);   // float4 W-loads/thread (4|2)
    __shared__ __align__(16) float As[KC][NT + 4];
    __shared__ __align__(16) float Ws[KC][MT + 4];

    const int tid  = threadIdx.x;
    const int tx   = tid % NG;
    const int ty   = tid / NG;
    const int nodeBase = blockIdx.x * NT;
    const int foff     = blockIdx.y * MT;

    // staging coords: f = tid*LD + i -> row = f>>3 (KC/4=8 chunks/row)
    const int arow = (tid * ALD) >> 3;
    const int ac0  = (tid * ALD) & 7;
    const int gn   = nodeBase + arow;
    const bool aok = gn < N;
    const float* aptr = A + (size_t)gn * K + ac0 * 4;
    const int wrow = (tid * WLD) >> 3;
    const int wc0  = (tid * WLD) & 7;
    const float* wptr = W + (size_t)(foff + wrow) * K + wc0 * 4;

    float acc[TN][TM];
#pragma unroll
    for (int i = 0; i < TN; ++i)
#pragma unroll
        for (int j = 0; j < TM; ++j) acc[i][j] = 0.f;

    float4 a_reg[ALD];
    float4 w_reg[WLD];
#pragma unroll
    for (int i = 0; i < ALD; ++i) a_reg[i] = make_float4(0.f, 0.f, 0.f, 0.f);

    // prologue: tile kc=0 into registers
    if (aok) {
#pragma unroll
        for (int i = 0; i < ALD; ++i) a_reg[i] = *(const float4*)(aptr + i * 4);
    }
#pragma unroll
    for (int i = 0; i < WLD; ++i) w_reg[i] = *(const float4*)(wptr + i * 4);

    for (int kc = 0; kc < K; kc += KC) {
        // commit staged registers to LDS (transposed, k-major rows)
#pragma unroll
        for (int i = 0; i < ALD; ++i) {
            const int c = ac0 + i;
            As[c * 4 + 0][arow] = a_reg[i].x;
            As[c * 4 + 1][arow] = a_reg[i].y;
            As[c * 4 + 2][arow] = a_reg[i].z;
            As[c * 4 + 3][arow] = a_reg[i].w;
        }
#pragma unroll
        for (int i = 0; i < WLD; ++i) {
            const int c = wc0 + i;
            Ws[c * 4 + 0][wrow] = w_reg[i].x;
            Ws[c * 4 + 1][wrow] = w_reg[i].y;
            Ws[c * 4 + 2][wrow] = w_reg[i].z;
            Ws[c * 4 + 3][wrow] = w_reg[i].w;
        }
        __syncthreads();

        // prefetch next tile: drains during the compute below
        if (kc + KC < K) {
            if (aok) {
#pragma unroll
                for (int i = 0; i < ALD; ++i)
                    a_reg[i] = *(const float4*)(aptr + kc + KC + i * 4);
            }
#pragma unroll
            for (int i = 0; i < WLD; ++i)
                w_reg[i] = *(const float4*)(wptr + kc + KC + i * 4);
        }

#pragma unroll 4
        for (int k = 0; k < KC; ++k) {
            float a[TN];
            float w[TM];
#pragma unroll
            for (int i4 = 0; i4 < TN / 4; ++i4) {
                float4 av = *(const float4*)&As[k][tx * TN + i4 * 4];
                a[i4 * 4 + 0] = av.x; a[i4 * 4 + 1] = av.y;
                a[i4 * 4 + 2] = av.z; a[i4 * 4 + 3] = av.w;
            }
#pragma unroll
            for (int j4 = 0; j4 < TM / 4; ++j4) {
                float4 wv = *(const float4*)&Ws[k][ty * TM + j4 * 4];
                w[j4 * 4 + 0] = wv.x; w[j4 * 4 + 1] = wv.y;
                w[j4 * 4 + 2] = wv.z; w[j4 * 4 + 3] = wv.w;
            }
#pragma unroll
            for (int i = 0; i < TN; ++i)
#pragma unroll
                for (int j = 0; j < TM; ++j) acc[i][j] = fmaf(a[i], w[j], acc[i][j]);
        }
        __syncthreads();
    }

#pragma unroll
    for (int i = 0; i < TN; ++i) {
        int node = nodeBase + tx * TN + i;
        if (node < N) {
            float* cp = C + (size_t)node * M + foff + ty * TM;
#pragma unroll
            for (int j4 = 0; j4 < TM / 4; ++j4) {
                float t[4];
#pragma unroll
                for (int c = 0; c < 4; ++c) {
                    float x = acc[i][j4 * 4 + c];
                    if constexpr (BIAS) x += bias[foff + ty * TM + j4 * 4 + c];
                    if constexpr (ACT == 1) x = fmaxf(x, 0.f);
                    if constexpr (ACT == 2) x = 1.f / (1.f + __expf(-x));
                    t[c] = x;
                }
                float4 v; v.x = t[0]; v.y = t[1]; v.z = t[2]; v.w = t[3];
                *(float4*)(cp + j4 * 4) = v;
            }
        }
    }
}

// ---------------- CSR build: deterministic counting sort -------------
// bucket b = dst >> 6; count index = b*128 + r*16 + g  (r = blockIdx&7,
// g = blockIdx>>3) => bucketBase[b] = pos[b*128]. Zero global atomics.

__global__ __launch_bounds__(256) void count_k(const int* __restrict__ ei,
                                               int* __restrict__ cnt,
                                               int NB, int E) {
    __shared__ int hist[784];
    const int tid = threadIdx.x;
    for (int i = tid; i < NB; i += 256) hist[i] = 0;
    __syncthreads();
    const int chunk = (E + NBLK - 1) / NBLK;
    const int lo = blockIdx.x * chunk;
    const int hi = min(lo + chunk, E);
    for (int e = lo + tid; e < hi; e += 256) {
        int d = ei[E + e];
        atomicAdd(&hist[d >> 6], 1);
    }
    __syncthreads();
    const int r = blockIdx.x & 7, g = blockIdx.x >> 3;
    for (int i = tid; i < NB; i += 256)
        cnt[i * NBLK + r * GRP + g] = hist[i];
}

__global__ __launch_bounds__(256) void scan1(const int* __restrict__ cnt,
                                             int* __restrict__ pos,
                                             int* __restrict__ bs, int n) {
    __shared__ int s[256];
    const int t = threadIdx.x;
    const int i0 = blockIdx.x * 512 + 2 * t;
    int c0 = (i0     < n) ? cnt[i0]     : 0;
    int c1 = (i0 + 1 < n) ? cnt[i0 + 1] : 0;
    int c = c0 + c1;
    s[t] = c;
    __syncthreads();
    for (int off = 1; off < 256; off <<= 1) {
        int v = (t >= off) ? s[t - off] : 0;
        __syncthreads();
        s[t] += v;
        __syncthreads();
    }
    int excl = s[t] - c;
    if (i0     < n) pos[i0]     = excl;
    if (i0 + 1 < n) pos[i0 + 1] = excl + c0;
    if (t == 255) bs[blockIdx.x] = s[255];
}

__global__ __launch_bounds__(256) void scan_tops(int* __restrict__ bs, int nb) {
    __shared__ int s[256];
    int t = threadIdx.x;
    int v = (t < nb) ? bs[t] : 0;
    s[t] = v;
    __syncthreads();
    for (int off = 1; off < 256; off <<= 1) {
        int u = (t >= off) ? s[t - off] : 0;
        __syncthreads();
        s[t] += u;
        __syncthreads();
    }
    if (t < nb) bs[t] = s[t] - v;
}

__global__ __launch_bounds__(256) void scan2(int* __restrict__ pos,
                                             const int* __restrict__ bs,
                                             int* __restrict__ bucketBase,
                                             int n, int NB, int E) {
    const int t = threadIdx.x;
    const int i0 = blockIdx.x * 512 + 2 * t;
    const int add = bs[blockIdx.x];
#pragma unroll
    for (int c = 0; c < 2; ++c) {
        int i = i0 + c;
        if (i < n) {
            int v = pos[i] + add;
            pos[i] = v;
            if ((i & (NBLK - 1)) == 0) bucketBase[i >> 7] = v;
        }
    }
    if (blockIdx.x == 0 && t == 0) bucketBase[NB] = E;
}

__global__ __launch_bounds__(256) void place_k(const int* __restrict__ ei,
                                               const float* __restrict__ w,
                                               const int* __restrict__ pos,
                                               int2* __restrict__ ebuf,
                                               int NB, int E) {
    __shared__ int cur[784];
    const int tid = threadIdx.x;
    const int r = blockIdx.x & 7, g = blockIdx.x >> 3;
    for (int i = tid; i < NB; i += 256) cur[i] = pos[i * NBLK + r * GRP + g];
    __syncthreads();
    const int chunk = (E + NBLK - 1) / NBLK;
    const int lo = blockIdx.x * chunk;
    const int hi = min(lo + chunk, E);
    for (int e = lo + tid; e < hi; e += 256) {
        int s = ei[e];
        int d = ei[E + e];
        float wv = w[e];
        int p = atomicAdd(&cur[d >> 6], 1);  // LDS atomic
        ebuf[p] = make_int2(s | ((d & 63) << 26), __float_as_int(wv));
    }
}

__global__ __launch_bounds__(256) void bucket_build(const int2* __restrict__ ebuf,
                                                    const int* __restrict__ bucketBase,
                                                    int2* __restrict__ sn,
                                                    int* __restrict__ row,
                                                    float* __restrict__ dinv,
                                                    int N, int E) {
    __shared__ int   lh[64];
    __shared__ float ldg[64];
    __shared__ int   sc[64];
    __shared__ int   lofs[64];
    const int tid  = threadIdx.x;
    const int base = bucketBase[blockIdx.x];
    const int end  = bucketBase[blockIdx.x + 1];

    if (tid < 64) { lh[tid] = 0; ldg[tid] = 0.f; }
    __syncthreads();
    for (int i = base + tid; i < end; i += 256) {
        int2 v = ebuf[i];
        int dl = ((unsigned)v.x) >> 26;
        atomicAdd(&lh[dl], 1);
        atomicAdd(&ldg[dl], __int_as_float(v.y));
    }
    __syncthreads();
    if (tid < 64) sc[tid] = lh[tid];
    __syncthreads();
    for (int off = 1; off < 64; off <<= 1) {
        int v = (tid < 64 && tid >= off) ? sc[tid - off] : 0;
        __syncthreads();
        if (tid < 64) sc[tid] += v;
        __syncthreads();
    }
    if (tid < 64) {
        int excl = sc[tid] - lh[tid];
        int d = (blockIdx.x << 6) + tid;
        if (d < N) {
            row[d]  = base + excl;
            dinv[d] = rsqrtf(fmaxf(1.0f + ldg[tid], 1e-12f));  // + self-loop
        }
        lofs[tid] = base + excl;
    }
    __syncthreads();
    for (int i = base + tid; i < end; i += 256) {
        int2 v = ebuf[i];
        unsigned u = (unsigned)v.x;
        int dl = u >> 26;
        int s  = u & 0x03FFFFFF;
        int p  = atomicAdd(&lofs[dl], 1);
        sn[p] = make_int2(s, v.y);
    }
    if (blockIdx.x == 0 && tid == 0) row[N] = E;
}

// payload.y <- w * dinv[src]
__global__ __launch_bounds__(256) void scale_pay(int2* __restrict__ sn,
                                                 const float* __restrict__ dinv,
                                                 int E) {
    int p = blockIdx.x * 256 + threadIdx.x;
    if (p < E) {
        int2 v = sn[p];
        sn[p] = make_int2(v.x, __float_as_int(__int_as_float(v.y) * dinv[v.x]));
    }
}

// ---------------- fused GCN aggregation (gather, no atomics) ---------
// out[i] = relu( (sum_e pay_e*t[src_e] + t[i]*dinv[i]) * dinv[i] + b )
__global__ __launch_bounds__(256) void gcn_agg(const float* __restrict__ t,
                                               const int2* __restrict__ sn,
                                               const int* __restrict__ row,
                                               const float* __restrict__ dinv,
                                               const float* __restrict__ bias,
                                               float* __restrict__ out, int N) {
    const int lane = threadIdx.x & 63;
    int i = __builtin_amdgcn_readfirstlane((int)(blockIdx.x * 4) + (threadIdx.x >> 6));
    if (i >= N) return;
    float di   = dinv[i];
    float self = t[(size_t)i * 64 + lane];
    float acc  = 0.f;
    int p  = row[i];
    int pe = row[i + 1];
    for (; p + 4 <= pe; p += 4) {
        int2 v0 = sn[p];
        int2 v1 = sn[p + 1];
        int2 v2 = sn[p + 2];
        int2 v3 = sn[p + 3];
        acc += t[(size_t)v0.x * 64 + lane] * __int_as_float(v0.y);
        acc += t[(size_t)v1.x * 64 + lane] * __int_as_float(v1.y);
        acc += t[(size_t)v2.x * 64 + lane] * __int_as_float(v2.y);
        acc += t[(size_t)v3.x * 64 + lane] * __int_as_float(v3.y);
    }
    for (; p < pe; ++p) {
        int2 v = sn[p];
        acc += t[(size_t)v.x * 64 + lane] * __int_as_float(v.y);
    }
    float x = (acc + self * di) * di + bias[lane];
    out[(size_t)i * 64 + lane] = fmaxf(x, 0.f);
}

// =====================================================================
extern "C" void kernel_launch(void* const* d_in, const int* in_sizes, int n_in,
                              void* d_out, int out_size, void* d_ws, size_t ws_size,
                              hipStream_t stream) {
    const float* x      = (const float*)d_in[0];
    const int*   ei     = (const int*)d_in[1];   // int32 per harness contract
    const float* ew     = (const float*)d_in[2];
    const float* enc1_w = (const float*)d_in[3];
    const float* enc1_b = (const float*)d_in[4];
    const float* enc2_w = (const float*)d_in[5];
    const float* enc2_b = (const float*)d_in[6];
    const float* gcn1_w = (const float*)d_in[7];
    const float* gcn1_b = (const float*)d_in[8];
    const float* gcn2_w = (const float*)d_in[9];
    const float* gcn2_b = (const float*)d_in[10];
    const float* dec1_w = (const float*)d_in[11];
    const float* dec1_b = (const float*)d_in[12];
    const float* dec2_w = (const float*)d_in[13];
    const float* dec2_b = (const float*)d_in[14];

    const int N  = in_sizes[0] / 256;    // 50000
    const int E  = in_sizes[2];          // 1600000
    const int NB = (N + 63) / 64;        // 782 buckets
    const int NCNT = NB * NBLK;          // 100096 counters
    const int NS   = (NCNT + 511) / 512; // 196 scan blocks

    // workspace (~40 MB):
    //  bufA [N*128 floats]: h1 -> { sn[E] int2 | ebuf[E] int2 (=bufC) } -> h5
    //  bufB [N*64]: h2/h3/h4 ; dinv[N]; row[N+1];
    //  cnt[NCNT]; pos[NCNT]; bucketBase[NB+1]; bs[256]
    float* ws   = (float*)d_ws;
    float* bufA = ws;
    int2*  sn   = (int2*)bufA;                  // E int2 (first half of bufA)
    float* bufC = bufA + (size_t)2 * E;         // N*64 floats (second half)
    int2*  ebuf = (int2*)bufC;                  // aliases bufC during build
    float* bufB = bufA + (size_t)N * 128;       // N*64
    float* dinv = bufB + (size_t)N * 64;        // N
    int*   row  = (int*)(dinv + N);             // N+1
    int*   cnt  = row + (N + 1);                // NCNT
    int*   pos  = cnt + NCNT;                   // NCNT
    int*   bucketBase = pos + NCNT;             // NB+1
    int*   bs   = bucketBase + (NB + 1);        // 256

    const int gemmGrid = (N + 127) / 128;       // 391
    const int nBlkE    = (E + 255) / 256;       // 6250

    // encoder
    gemm_rt<256, 128, 128, 1, true, 8, 8><<<dim3(gemmGrid, 1), 256, 0, stream>>>(
        x, enc1_w, enc1_b, bufA, N);
    gemm_rt<128, 64, 64, 1, true, 4, 8><<<dim3(gemmGrid, 1), 256, 0, stream>>>(
        bufA, enc2_w, enc2_b, bufB, N);

    // CSR build, zero global atomics (shared by both GCN layers)
    count_k<<<NBLK, 256, 0, stream>>>(ei, cnt, NB, E);
    scan1<<<NS, 256, 0, stream>>>(cnt, pos, bs, NCNT);
    scan_tops<<<1, 256, 0, stream>>>(bs, NS);
    scan2<<<NS, 256, 0, stream>>>(pos, bs, bucketBase, NCNT, NB, E);
    place_k<<<NBLK, 256, 0, stream>>>(ei, ew, pos, ebuf, NB, E);
    bucket_build<<<NB, 256, 0, stream>>>(ebuf, bucketBase, sn, row, dinv, N, E);
    scale_pay<<<nBlkE, 256, 0, stream>>>(sn, dinv, E);

    // GCN layer 1
    gemm_rt<64, 64, 64, 0, false, 4, 8><<<dim3(gemmGrid, 1), 256, 0, stream>>>(
        bufB, gcn1_w, nullptr, bufC, N);
    gcn_agg<<<(N + 3) / 4, 256, 0, stream>>>(bufC, sn, row, dinv, gcn1_b, bufB, N);

    // GCN layer 2
    gemm_rt<64, 64, 64, 0, false, 4, 8><<<dim3(gemmGrid, 1), 256, 0, stream>>>(
        bufB, gcn2_w, nullptr, bufC, N);
    gcn_agg<<<(N + 3) / 4, 256, 0, stream>>>(bufC, sn, row, dinv, gcn2_b, bufB, N);

    // decoder
    gemm_rt<64, 128, 128, 1, true, 8, 8><<<dim3(gemmGrid, 1), 256, 0, stream>>>(
        bufB, dec1_w, dec1_b, bufA, N);
    gemm_rt<128, 128, 256, 2, true, 8, 8><<<dim3(gemmGrid, 2), 256, 0, stream>>>(
        bufA, dec2_w, dec2_b, (float*)d_out, N);
}

// Round 4
// 494.860 us; speedup vs baseline: 1.0051x; 1.0051x over previous
//
#include <hip/hip_runtime.h>

// =====================================================================
// GraphAutoEncoder forward (all fp32). GCN via CSR build + gather.
// R10: reg double-buffer staging. R11: fat 8x8 register tiles (LDS-pipe
// ratio), NT=128 KC=32. R13: R11's A-frag read As[k][tx*8] was a 4-WAY
// BANK CONFLICT (32B stride, 16 banks idle -> SQ_LDS_BANK_CONFLICT
// 1.2M->4.0M, dec2 regressed to 65us). Fix: thread's 8 nodes = two
// groups of 4 CONTIGUOUS nodes at NT/2 offset -> 2x ds_read_b128 at
// dense 16B stride (2-way = free). W-read (ty*8, 4 uniq addrs, disjoint
// bank quads, broadcast) already conflict-free.
// =====================================================================

constexpr int NBLK = 128;           // scatter blocks (chunk = E/128)
constexpr int GRP  = NBLK / 8;      // block-groups per XCD residue

// ---------------- GEMM: C[:,foff:foff+MT] = act(A @ W^T + b) ---------
// node tile = 128, KC=32, MT per blockIdx.y. 256 thr = (128/TN)*(MT/TM)
// TN is split into TN/4 groups of 4 contiguous nodes, group stride NT/(TN/4).
template <int K, int MT, int M, int ACT, bool BIAS, int TN, int TM>
__global__ __launch_bounds__(256) void gemm_rt(const float* __restrict__ A,
                                               const float* __restrict__ W,
                                               const float* __restrict__ bias,
                                               float* __restrict__ C, int N) {
    constexpr int KC  = 32;
    constexpr int NT  = 128;
    constexpr int NG  = NT / TN;                 // node groups
    constexpr int FG  = MT / TM;                 // feature groups
    static_assert(NG * FG == 256, "bad tile");
    constexpr int GCNT = TN / 4;                 // node sub-groups per thread
    constexpr int GSTR = NT / GCNT;              // stride between sub-groups
    constexpr int ALD = (NT * KC) / (4 * 256);   // float4 A-loads/thread = 4
    constexpr int WLD = (MT * KC) / (4 * 256);   // float4 W-loads/thread (4|2)
    __shared__ __align__(16) float As[KC][NT + 4];
    __shared__ __align__(16) float Ws[KC][MT + 4];

    const int tid  = threadIdx.x;
    const int tx   = tid % NG;
    const int ty   = tid / NG;
    const int nodeBase = blockIdx.x * NT;
    const int foff     = blockIdx.y * MT;

    // staging coords: f = tid*LD + i -> row = f>>3 (KC/4=8 chunks/row)
    const int arow = (tid * ALD) >> 3;
    const int ac0  = (tid * ALD) & 7;
    const int gn   = nodeBase + arow;
    const bool aok = gn < N;
    const float* aptr = A + (size_t)gn * K + ac0 * 4;
    const int wrow = (tid * WLD) >> 3;
    const int wc0  = (tid * WLD) & 7;
    const float* wptr = W + (size_t)(foff + wrow) * K + wc0 * 4;

    float acc[TN][TM];
#pragma unroll
    for (int i = 0; i < TN; ++i)
#pragma unroll
        for (int j = 0; j < TM; ++j) acc[i][j] = 0.f;

    float4 a_reg[ALD];
    float4 w_reg[WLD];
#pragma unroll
    for (int i = 0; i < ALD; ++i) a_reg[i] = make_float4(0.f, 0.f, 0.f, 0.f);

    // prologue: tile kc=0 into registers
    if (aok) {
#pragma unroll
        for (int i = 0; i < ALD; ++i) a_reg[i] = *(const float4*)(aptr + i * 4);
    }
#pragma unroll
    for (int i = 0; i < WLD; ++i) w_reg[i] = *(const float4*)(wptr + i * 4);

    for (int kc = 0; kc < K; kc += KC) {
        // commit staged registers to LDS (transposed, k-major rows)
#pragma unroll
        for (int i = 0; i < ALD; ++i) {
            const int c = ac0 + i;
            As[c * 4 + 0][arow] = a_reg[i].x;
            As[c * 4 + 1][arow] = a_reg[i].y;
            As[c * 4 + 2][arow] = a_reg[i].z;
            As[c * 4 + 3][arow] = a_reg[i].w;
        }
#pragma unroll
        for (int i = 0; i < WLD; ++i) {
            const int c = wc0 + i;
            Ws[c * 4 + 0][wrow] = w_reg[i].x;
            Ws[c * 4 + 1][wrow] = w_reg[i].y;
            Ws[c * 4 + 2][wrow] = w_reg[i].z;
            Ws[c * 4 + 3][wrow] = w_reg[i].w;
        }
        __syncthreads();

        // prefetch next tile: drains during the compute below
        if (kc + KC < K) {
            if (aok) {
#pragma unroll
                for (int i = 0; i < ALD; ++i)
                    a_reg[i] = *(const float4*)(aptr + kc + KC + i * 4);
            }
#pragma unroll
            for (int i = 0; i < WLD; ++i)
                w_reg[i] = *(const float4*)(wptr + kc + KC + i * 4);
        }

#pragma unroll 4
        for (int k = 0; k < KC; ++k) {
            float a[TN];
            float w[TM];
#pragma unroll
            for (int g = 0; g < GCNT; ++g) {
                float4 av = *(const float4*)&As[k][g * GSTR + tx * 4];  // dense, free
                a[g * 4 + 0] = av.x; a[g * 4 + 1] = av.y;
                a[g * 4 + 2] = av.z; a[g * 4 + 3] = av.w;
            }
#pragma unroll
            for (int j4 = 0; j4 < TM / 4; ++j4) {
                float4 wv = *(const float4*)&Ws[k][ty * TM + j4 * 4];   // broadcast
                w[j4 * 4 + 0] = wv.x; w[j4 * 4 + 1] = wv.y;
                w[j4 * 4 + 2] = wv.z; w[j4 * 4 + 3] = wv.w;
            }
#pragma unroll
            for (int i = 0; i < TN; ++i)
#pragma unroll
                for (int j = 0; j < TM; ++j) acc[i][j] = fmaf(a[i], w[j], acc[i][j]);
        }
        __syncthreads();
    }

#pragma unroll
    for (int g = 0; g < GCNT; ++g) {
#pragma unroll
        for (int ii = 0; ii < 4; ++ii) {
            int node = nodeBase + g * GSTR + tx * 4 + ii;
            if (node < N) {
                float* cp = C + (size_t)node * M + foff + ty * TM;
#pragma unroll
                for (int j4 = 0; j4 < TM / 4; ++j4) {
                    float t[4];
#pragma unroll
                    for (int c = 0; c < 4; ++c) {
                        float x = acc[g * 4 + ii][j4 * 4 + c];
                        if constexpr (BIAS) x += bias[foff + ty * TM + j4 * 4 + c];
                        if constexpr (ACT == 1) x = fmaxf(x, 0.f);
                        if constexpr (ACT == 2) x = 1.f / (1.f + __expf(-x));
                        t[c] = x;
                    }
                    float4 v; v.x = t[0]; v.y = t[1]; v.z = t[2]; v.w = t[3];
                    *(float4*)(cp + j4 * 4) = v;
                }
            }
        }
    }
}

// ---------------- CSR build: deterministic counting sort -------------
// bucket b = dst >> 6; count index = b*128 + r*16 + g  (r = blockIdx&7,
// g = blockIdx>>3) => bucketBase[b] = pos[b*128]. Zero global atomics.

__global__ __launch_bounds__(256) void count_k(const int* __restrict__ ei,
                                               int* __restrict__ cnt,
                                               int NB, int E) {
    __shared__ int hist[784];
    const int tid = threadIdx.x;
    for (int i = tid; i < NB; i += 256) hist[i] = 0;
    __syncthreads();
    const int chunk = (E + NBLK - 1) / NBLK;
    const int lo = blockIdx.x * chunk;
    const int hi = min(lo + chunk, E);
    for (int e = lo + tid; e < hi; e += 256) {
        int d = ei[E + e];
        atomicAdd(&hist[d >> 6], 1);
    }
    __syncthreads();
    const int r = blockIdx.x & 7, g = blockIdx.x >> 3;
    for (int i = tid; i < NB; i += 256)
        cnt[i * NBLK + r * GRP + g] = hist[i];
}

__global__ __launch_bounds__(256) void scan1(const int* __restrict__ cnt,
                                             int* __restrict__ pos,
                                             int* __restrict__ bs, int n) {
    __shared__ int s[256];
    const int t = threadIdx.x;
    const int i0 = blockIdx.x * 512 + 2 * t;
    int c0 = (i0     < n) ? cnt[i0]     : 0;
    int c1 = (i0 + 1 < n) ? cnt[i0 + 1] : 0;
    int c = c0 + c1;
    s[t] = c;
    __syncthreads();
    for (int off = 1; off < 256; off <<= 1) {
        int v = (t >= off) ? s[t - off] : 0;
        __syncthreads();
        s[t] += v;
        __syncthreads();
    }
    int excl = s[t] - c;
    if (i0     < n) pos[i0]     = excl;
    if (i0 + 1 < n) pos[i0 + 1] = excl + c0;
    if (t == 255) bs[blockIdx.x] = s[255];
}

__global__ __launch_bounds__(256) void scan_tops(int* __restrict__ bs, int nb) {
    __shared__ int s[256];
    int t = threadIdx.x;
    int v = (t < nb) ? bs[t] : 0;
    s[t] = v;
    __syncthreads();
    for (int off = 1; off < 256; off <<= 1) {
        int u = (t >= off) ? s[t - off] : 0;
        __syncthreads();
        s[t] += u;
        __syncthreads();
    }
    if (t < nb) bs[t] = s[t] - v;
}

__global__ __launch_bounds__(256) void scan2(int* __restrict__ pos,
                                             const int* __restrict__ bs,
                                             int* __restrict__ bucketBase,
                                             int n, int NB, int E) {
    const int t = threadIdx.x;
    const int i0 = blockIdx.x * 512 + 2 * t;
    const int add = bs[blockIdx.x];
#pragma unroll
    for (int c = 0; c < 2; ++c) {
        int i = i0 + c;
        if (i < n) {
            int v = pos[i] + add;
            pos[i] = v;
            if ((i & (NBLK - 1)) == 0) bucketBase[i >> 7] = v;
        }
    }
    if (blockIdx.x == 0 && t == 0) bucketBase[NB] = E;
}

__global__ __launch_bounds__(256) void place_k(const int* __restrict__ ei,
                                               const float* __restrict__ w,
                                               const int* __restrict__ pos,
                                               int2* __restrict__ ebuf,
                                               int NB, int E) {
    __shared__ int cur[784];
    const int tid = threadIdx.x;
    const int r = blockIdx.x & 7, g = blockIdx.x >> 3;
    for (int i = tid; i < NB; i += 256) cur[i] = pos[i * NBLK + r * GRP + g];
    __syncthreads();
    const int chunk = (E + NBLK - 1) / NBLK;
    const int lo = blockIdx.x * chunk;
    const int hi = min(lo + chunk, E);
    for (int e = lo + tid; e < hi; e += 256) {
        int s = ei[e];
        int d = ei[E + e];
        float wv = w[e];
        int p = atomicAdd(&cur[d >> 6], 1);  // LDS atomic
        ebuf[p] = make_int2(s | ((d & 63) << 26), __float_as_int(wv));
    }
}

__global__ __launch_bounds__(256) void bucket_build(const int2* __restrict__ ebuf,
                                                    const int* __restrict__ bucketBase,
                                                    int2* __restrict__ sn,
                                                    int* __restrict__ row,
                                                    float* __restrict__ dinv,
                                                    int N, int E) {
    __shared__ int   lh[64];
    __shared__ float ldg[64];
    __shared__ int   sc[64];
    __shared__ int   lofs[64];
    const int tid  = threadIdx.x;
    const int base = bucketBase[blockIdx.x];
    const int end  = bucketBase[blockIdx.x + 1];

    if (tid < 64) { lh[tid] = 0; ldg[tid] = 0.f; }
    __syncthreads();
    for (int i = base + tid; i < end; i += 256) {
        int2 v = ebuf[i];
        int dl = ((unsigned)v.x) >> 26;
        atomicAdd(&lh[dl], 1);
        atomicAdd(&ldg[dl], __int_as_float(v.y));
    }
    __syncthreads();
    if (tid < 64) sc[tid] = lh[tid];
    __syncthreads();
    for (int off = 1; off < 64; off <<= 1) {
        int v = (tid < 64 && tid >= off) ? sc[tid - off] : 0;
        __syncthreads();
        if (tid < 64) sc[tid] += v;
        __syncthreads();
    }
    if (tid < 64) {
        int excl = sc[tid] - lh[tid];
        int d = (blockIdx.x << 6) + tid;
        if (d < N) {
            row[d]  = base + excl;
            dinv[d] = rsqrtf(fmaxf(1.0f + ldg[tid], 1e-12f));  // + self-loop
        }
        lofs[tid] = base + excl;
    }
    __syncthreads();
    for (int i = base + tid; i < end; i += 256) {
        int2 v = ebuf[i];
        unsigned u = (unsigned)v.x;
        int dl = u >> 26;
        int s  = u & 0x03FFFFFF;
        int p  = atomicAdd(&lofs[dl], 1);
        sn[p] = make_int2(s, v.y);
    }
    if (blockIdx.x == 0 && tid == 0) row[N] = E;
}

// payload.y <- w * dinv[src]
__global__ __launch_bounds__(256) void scale_pay(int2* __restrict__ sn,
                                                 const float* __restrict__ dinv,
                                                 int E) {
    int p = blockIdx.x * 256 + threadIdx.x;
    if (p < E) {
        int2 v = sn[p];
        sn[p] = make_int2(v.x, __float_as_int(__int_as_float(v.y) * dinv[v.x]));
    }
}

// ---------------- fused GCN aggregation (gather, no atomics) ---------
// out[i] = relu( (sum_e pay_e*t[src_e] + t[i]*dinv[i]) * dinv[i] + b )
__global__ __launch_bounds__(256) void gcn_agg(const float* __restrict__ t,
                                               const int2* __restrict__ sn,
                                               const int* __restrict__ row,
                                               const float* __restrict__ dinv,
                                               const float* __restrict__ bias,
                                               float* __restrict__ out, int N) {
    const int lane = threadIdx.x & 63;
    int i = __builtin_amdgcn_readfirstlane((int)(blockIdx.x * 4) + (threadIdx.x >> 6));
    if (i >= N) return;
    float di   = dinv[i];
    float self = t[(size_t)i * 64 + lane];
    float acc  = 0.f;
    int p  = row[i];
    int pe = row[i + 1];
    for (; p + 4 <= pe; p += 4) {
        int2 v0 = sn[p];
        int2 v1 = sn[p + 1];
        int2 v2 = sn[p + 2];
        int2 v3 = sn[p + 3];
        acc += t[(size_t)v0.x * 64 + lane] * __int_as_float(v0.y);
        acc += t[(size_t)v1.x * 64 + lane] * __int_as_float(v1.y);
        acc += t[(size_t)v2.x * 64 + lane] * __int_as_float(v2.y);
        acc += t[(size_t)v3.x * 64 + lane] * __int_as_float(v3.y);
    }
    for (; p < pe; ++p) {
        int2 v = sn[p];
        acc += t[(size_t)v.x * 64 + lane] * __int_as_float(v.y);
    }
    float x = (acc + self * di) * di + bias[lane];
    out[(size_t)i * 64 + lane] = fmaxf(x, 0.f);
}

// =====================================================================
extern "C" void kernel_launch(void* const* d_in, const int* in_sizes, int n_in,
                              void* d_out, int out_size, void* d_ws, size_t ws_size,
                              hipStream_t stream) {
    const float* x      = (const float*)d_in[0];
    const int*   ei     = (const int*)d_in[1];   // int32 per harness contract
    const float* ew     = (const float*)d_in[2];
    const float* enc1_w = (const float*)d_in[3];
    const float* enc1_b = (const float*)d_in[4];
    const float* enc2_w = (const float*)d_in[5];
    const float* enc2_b = (const float*)d_in[6];
    const float* gcn1_w = (const float*)d_in[7];
    const float* gcn1_b = (const float*)d_in[8];
    const float* gcn2_w = (const float*)d_in[9];
    const float* gcn2_b = (const float*)d_in[10];
    const float* dec1_w = (const float*)d_in[11];
    const float* dec1_b = (const float*)d_in[12];
    const float* dec2_w = (const float*)d_in[13];
    const float* dec2_b = (const float*)d_in[14];

    const int N  = in_sizes[0] / 256;    // 50000
    const int E  = in_sizes[2];          // 1600000
    const int NB = (N + 63) / 64;        // 782 buckets
    const int NCNT = NB * NBLK;          // 100096 counters
    const int NS   = (NCNT + 511) / 512; // 196 scan blocks

    // workspace (~40 MB):
    //  bufA [N*128 floats]: h1 -> { sn[E] int2 | ebuf[E] int2 (=bufC) } -> h5
    //  bufB [N*64]: h2/h3/h4 ; dinv[N]; row[N+1];
    //  cnt[NCNT]; pos[NCNT]; bucketBase[NB+1]; bs[256]
    float* ws   = (float*)d_ws;
    float* bufA = ws;
    int2*  sn   = (int2*)bufA;                  // E int2 (first half of bufA)
    float* bufC = bufA + (size_t)2 * E;         // N*64 floats (second half)
    int2*  ebuf = (int2*)bufC;                  // aliases bufC during build
    float* bufB = bufA + (size_t)N * 128;       // N*64
    float* dinv = bufB + (size_t)N * 64;        // N
    int*   row  = (int*)(dinv + N);             // N+1
    int*   cnt  = row + (N + 1);                // NCNT
    int*   pos  = cnt + NCNT;                   // NCNT
    int*   bucketBase = pos + NCNT;             // NB+1
    int*   bs   = bucketBase + (NB + 1);        // 256

    const int gemmGrid = (N + 127) / 128;       // 391
    const int nBlkE    = (E + 255) / 256;       // 6250

    // encoder
    gemm_rt<256, 128, 128, 1, true, 8, 8><<<dim3(gemmGrid, 1), 256, 0, stream>>>(
        x, enc1_w, enc1_b, bufA, N);
    gemm_rt<128, 64, 64, 1, true, 4, 8><<<dim3(gemmGrid, 1), 256, 0, stream>>>(
        bufA, enc2_w, enc2_b, bufB, N);

    // CSR build, zero global atomics (shared by both GCN layers)
    count_k<<<NBLK, 256, 0, stream>>>(ei, cnt, NB, E);
    scan1<<<NS, 256, 0, stream>>>(cnt, pos, bs, NCNT);
    scan_tops<<<1, 256, 0, stream>>>(bs, NS);
    scan2<<<NS, 256, 0, stream>>>(pos, bs, bucketBase, NCNT, NB, E);
    place_k<<<NBLK, 256, 0, stream>>>(ei, ew, pos, ebuf, NB, E);
    bucket_build<<<NB, 256, 0, stream>>>(ebuf, bucketBase, sn, row, dinv, N, E);
    scale_pay<<<nBlkE, 256, 0, stream>>>(sn, dinv, E);

    // GCN layer 1
    gemm_rt<64, 64, 64, 0, false, 4, 8><<<dim3(gemmGrid, 1), 256, 0, stream>>>(
        bufB, gcn1_w, nullptr, bufC, N);
    gcn_agg<<<(N + 3) / 4, 256, 0, stream>>>(bufC, sn, row, dinv, gcn1_b, bufB, N);

    // GCN layer 2
    gemm_rt<64, 64, 64, 0, false, 4, 8><<<dim3(gemmGrid, 1), 256, 0, stream>>>(
        bufB, gcn2_w, nullptr, bufC, N);
    gcn_agg<<<(N + 3) / 4, 256, 0, stream>>>(bufC, sn, row, dinv, gcn2_b, bufB, N);

    // decoder
    gemm_rt<64, 128, 128, 1, true, 8, 8><<<dim3(gemmGrid, 1), 256, 0, stream>>>(
        bufB, dec1_w, dec1_b, bufA, N);
    gemm_rt<128, 128, 256, 2, true, 8, 8><<<dim3(gemmGrid, 2), 256, 0, stream>>>(
        bufA, dec2_w, dec2_b, (float*)d_out, N);
}

// Round 5
// 462.079 us; speedup vs baseline: 1.0764x; 1.0709x over previous
//
#include <hip/hip_runtime.h>

// =====================================================================
// GraphAutoEncoder forward. GCN via CSR build + gather (unchanged).
// R11-R13: vector-fp32 GEMM plateaued at VALUBusy ~44% across three
// tilings -> vector ALU path is at its practical ceiling. R14: GEMMs
// moved to MFMA via split-bf16 (x = hi+lo; A*B ~= Ah*Bh + Ah*Bl + Al*Bh,
// 3 MFMAs at 2.5PF rate = ~830 TF effective fp32, vs 157 TF vector).
// Split residual ~2^-16 -> dot error ~1e-4 << 0.0039 absmax budget.
// Geometry: block 256 thr = 4 waves (2Mx2N), BM=128 nodes, BN=64 feats,
// KC=64. Per wave: 4x2 frags of 16x16x32, acc 32 VGPR. LDS 55KB ->
// 2 blocks/CU. fp32 in/out everywhere (split in staging regs): no
// change to CSR build / gcn_agg / buffers.
// =====================================================================

constexpr int NBLK = 128;           // scatter blocks (chunk = E/128)
constexpr int GRP  = NBLK / 8;      // block-groups per XCD residue

typedef __attribute__((ext_vector_type(8))) short bf16x8;
typedef __attribute__((ext_vector_type(4))) float f32x4;

// split two fp32 into packed-bf16 hi pair + lo pair (truncation split;
// hi = top 16 bits, lo = bf16(f - hi), residual <= 2^-16 |f|)
__device__ inline void split2(float f0, float f1, unsigned& hp, unsigned& lp) {
    unsigned u0 = __float_as_uint(f0), u1 = __float_as_uint(f1);
    hp = (u1 & 0xFFFF0000u) | (u0 >> 16);
    float r0 = f0 - __uint_as_float(u0 & 0xFFFF0000u);
    float r1 = f1 - __uint_as_float(u1 & 0xFFFF0000u);
    lp = (__float_as_uint(r1) & 0xFFFF0000u) | (__float_as_uint(r0) >> 16);
}

// ---------------- GEMM: C[:,foff:+64] = act(A @ W^T + b), MFMA ------
// A [N][K] fp32, W [M][K] fp32. grid = (ceil(N/128), M/64).
template <int K, int M, int ACT, bool BIAS>  // ACT: 0 none,1 relu,2 sigmoid
__global__ __launch_bounds__(256) void gemm_mf(const float* __restrict__ A,
                                               const float* __restrict__ W,
                                               const float* __restrict__ bias,
                                               float* __restrict__ C, int N) {
    static_assert(K % 64 == 0, "K%64");
    constexpr int KC = 64;
    // uint = 2 bf16 along k. row = 32 uints (64 k) + 4 pad -> 144B rows.
    __shared__ unsigned Ah[128][36];
    __shared__ unsigned Al[128][36];
    __shared__ unsigned Wh[64][36];
    __shared__ unsigned Wl[64][36];

    const int tid      = threadIdx.x;
    const int nodeBase = blockIdx.x * 128;
    const int foff     = blockIdx.y * 64;

    // staging map (coalesced): chunk q*256+tid -> row = q*16 + (tid>>4),
    // float4 col = tid&15 (16 threads span one row's 64 k).
    const int srow = tid >> 4;          // 0..15 (row offset within q-stripe)
    const int sc4  = tid & 15;          // float4 column
    float4 av[8];
    float4 wv[4];

    // prologue: tile kc=0 into registers
#pragma unroll
    for (int q = 0; q < 8; ++q) {
        const int r  = q * 16 + srow;
        const int gn = nodeBase + r;
        av[q] = (gn < N) ? *(const float4*)(A + (size_t)gn * K + sc4 * 4)
                         : make_float4(0.f, 0.f, 0.f, 0.f);
    }
#pragma unroll
    for (int q = 0; q < 4; ++q) {
        const int r = q * 16 + srow;
        wv[q] = *(const float4*)(W + (size_t)(foff + r) * K + sc4 * 4);
    }

    f32x4 acc[4][2];
#pragma unroll
    for (int mf = 0; mf < 4; ++mf)
#pragma unroll
        for (int nf = 0; nf < 2; ++nf) acc[mf][nf] = (f32x4)0.f;

    const int lane = tid & 63;
    const int wid  = tid >> 6;
    const int wm   = wid >> 1;          // wave M index (0..1)
    const int wn   = wid & 1;           // wave N index (0..1)
    const int fr   = lane & 15;         // fragment row/col
    const int fg   = lane >> 4;         // k-group (0..3)

    for (int kc = 0; kc < K; kc += KC) {
        // commit staged regs -> LDS bf16 planes
#pragma unroll
        for (int q = 0; q < 8; ++q) {
            unsigned h0, l0, h1, l1;
            split2(av[q].x, av[q].y, h0, l0);
            split2(av[q].z, av[q].w, h1, l1);
            const int r = q * 16 + srow;
            Ah[r][sc4 * 2] = h0; Ah[r][sc4 * 2 + 1] = h1;
            Al[r][sc4 * 2] = l0; Al[r][sc4 * 2 + 1] = l1;
        }
#pragma unroll
        for (int q = 0; q < 4; ++q) {
            unsigned h0, l0, h1, l1;
            split2(wv[q].x, wv[q].y, h0, l0);
            split2(wv[q].z, wv[q].w, h1, l1);
            const int r = q * 16 + srow;
            Wh[r][sc4 * 2] = h0; Wh[r][sc4 * 2 + 1] = h1;
            Wl[r][sc4 * 2] = l0; Wl[r][sc4 * 2 + 1] = l1;
        }
        __syncthreads();

        // prefetch next tile (drains during MFMA below)
        if (kc + KC < K) {
#pragma unroll
            for (int q = 0; q < 8; ++q) {
                const int r  = q * 16 + srow;
                const int gn = nodeBase + r;
                av[q] = (gn < N)
                    ? *(const float4*)(A + (size_t)gn * K + kc + KC + sc4 * 4)
                    : make_float4(0.f, 0.f, 0.f, 0.f);
            }
#pragma unroll
            for (int q = 0; q < 4; ++q) {
                const int r = q * 16 + srow;
                wv[q] = *(const float4*)(W + (size_t)(foff + r) * K + kc + KC + sc4 * 4);
            }
        }

        // MFMA over this K-tile: 2 k-frags x (4m x 2n) x 3 splits
#pragma unroll
        for (int kf = 0; kf < 2; ++kf) {
            bf16x8 ah[4], alo[4], bh[2], blo[2];
#pragma unroll
            for (int mf = 0; mf < 4; ++mf) {
                const int r = wm * 64 + mf * 16 + fr;
                ah[mf]  = *(const bf16x8*)&Ah[r][kf * 16 + fg * 4];
                alo[mf] = *(const bf16x8*)&Al[r][kf * 16 + fg * 4];
            }
#pragma unroll
            for (int nf = 0; nf < 2; ++nf) {
                const int r = wn * 32 + nf * 16 + fr;
                bh[nf]  = *(const bf16x8*)&Wh[r][kf * 16 + fg * 4];
                blo[nf] = *(const bf16x8*)&Wl[r][kf * 16 + fg * 4];
            }
#pragma unroll
            for (int mf = 0; mf < 4; ++mf)
#pragma unroll
                for (int nf = 0; nf < 2; ++nf) {
                    acc[mf][nf] = __builtin_amdgcn_mfma_f32_16x16x32_bf16(
                        ah[mf], bh[nf], acc[mf][nf], 0, 0, 0);
                    acc[mf][nf] = __builtin_amdgcn_mfma_f32_16x16x32_bf16(
                        alo[mf], bh[nf], acc[mf][nf], 0, 0, 0);
                    acc[mf][nf] = __builtin_amdgcn_mfma_f32_16x16x32_bf16(
                        ah[mf], blo[nf], acc[mf][nf], 0, 0, 0);
                }
        }
        __syncthreads();
    }

    // epilogue: D[row=(lane>>4)*4+i][col=lane&15] per frag (m89-verified)
#pragma unroll
    for (int nf = 0; nf < 2; ++nf) {
        const int feat = foff + wn * 32 + nf * 16 + fr;
        const float bv = BIAS ? bias[feat] : 0.f;
#pragma unroll
        for (int mf = 0; mf < 4; ++mf) {
            const int node0 = nodeBase + wm * 64 + mf * 16 + fg * 4;
#pragma unroll
            for (int i = 0; i < 4; ++i) {
                const int node = node0 + i;
                if (node < N) {
                    float x = acc[mf][nf][i] + bv;
                    if constexpr (ACT == 1) x = fmaxf(x, 0.f);
                    if constexpr (ACT == 2) x = 1.f / (1.f + __expf(-x));
                    C[(size_t)node * M + feat] = x;
                }
            }
        }
    }
}

// ---------------- CSR build: deterministic counting sort -------------
// bucket b = dst >> 6; count index = b*128 + r*16 + g  (r = blockIdx&7,
// g = blockIdx>>3) => bucketBase[b] = pos[b*128]. Zero global atomics.

__global__ __launch_bounds__(256) void count_k(const int* __restrict__ ei,
                                               int* __restrict__ cnt,
                                               int NB, int E) {
    __shared__ int hist[784];
    const int tid = threadIdx.x;
    for (int i = tid; i < NB; i += 256) hist[i] = 0;
    __syncthreads();
    const int chunk = (E + NBLK - 1) / NBLK;
    const int lo = blockIdx.x * chunk;
    const int hi = min(lo + chunk, E);
    for (int e = lo + tid; e < hi; e += 256) {
        int d = ei[E + e];
        atomicAdd(&hist[d >> 6], 1);
    }
    __syncthreads();
    const int r = blockIdx.x & 7, g = blockIdx.x >> 3;
    for (int i = tid; i < NB; i += 256)
        cnt[i * NBLK + r * GRP + g] = hist[i];
}

__global__ __launch_bounds__(256) void scan1(const int* __restrict__ cnt,
                                             int* __restrict__ pos,
                                             int* __restrict__ bs, int n) {
    __shared__ int s[256];
    const int t = threadIdx.x;
    const int i0 = blockIdx.x * 512 + 2 * t;
    int c0 = (i0     < n) ? cnt[i0]     : 0;
    int c1 = (i0 + 1 < n) ? cnt[i0 + 1] : 0;
    int c = c0 + c1;
    s[t] = c;
    __syncthreads();
    for (int off = 1; off < 256; off <<= 1) {
        int v = (t >= off) ? s[t - off] : 0;
        __syncthreads();
        s[t] += v;
        __syncthreads();
    }
    int excl = s[t] - c;
    if (i0     < n) pos[i0]     = excl;
    if (i0 + 1 < n) pos[i0 + 1] = excl + c0;
    if (t == 255) bs[blockIdx.x] = s[255];
}

__global__ __launch_bounds__(256) void scan_tops(int* __restrict__ bs, int nb) {
    __shared__ int s[256];
    int t = threadIdx.x;
    int v = (t < nb) ? bs[t] : 0;
    s[t] = v;
    __syncthreads();
    for (int off = 1; off < 256; off <<= 1) {
        int u = (t >= off) ? s[t - off] : 0;
        __syncthreads();
        s[t] += u;
        __syncthreads();
    }
    if (t < nb) bs[t] = s[t] - v;
}

__global__ __launch_bounds__(256) void scan2(int* __restrict__ pos,
                                             const int* __restrict__ bs,
                                             int* __restrict__ bucketBase,
                                             int n, int NB, int E) {
    const int t = threadIdx.x;
    const int i0 = blockIdx.x * 512 + 2 * t;
    const int add = bs[blockIdx.x];
#pragma unroll
    for (int c = 0; c < 2; ++c) {
        int i = i0 + c;
        if (i < n) {
            int v = pos[i] + add;
            pos[i] = v;
            if ((i & (NBLK - 1)) == 0) bucketBase[i >> 7] = v;
        }
    }
    if (blockIdx.x == 0 && t == 0) bucketBase[NB] = E;
}

__global__ __launch_bounds__(256) void place_k(const int* __restrict__ ei,
                                               const float* __restrict__ w,
                                               const int* __restrict__ pos,
                                               int2* __restrict__ ebuf,
                                               int NB, int E) {
    __shared__ int cur[784];
    const int tid = threadIdx.x;
    const int r = blockIdx.x & 7, g = blockIdx.x >> 3;
    for (int i = tid; i < NB; i += 256) cur[i] = pos[i * NBLK + r * GRP + g];
    __syncthreads();
    const int chunk = (E + NBLK - 1) / NBLK;
    const int lo = blockIdx.x * chunk;
    const int hi = min(lo + chunk, E);
    for (int e = lo + tid; e < hi; e += 256) {
        int s = ei[e];
        int d = ei[E + e];
        float wv = w[e];
        int p = atomicAdd(&cur[d >> 6], 1);  // LDS atomic
        ebuf[p] = make_int2(s | ((d & 63) << 26), __float_as_int(wv));
    }
}

__global__ __launch_bounds__(256) void bucket_build(const int2* __restrict__ ebuf,
                                                    const int* __restrict__ bucketBase,
                                                    int2* __restrict__ sn,
                                                    int* __restrict__ row,
                                                    float* __restrict__ dinv,
                                                    int N, int E) {
    __shared__ int   lh[64];
    __shared__ float ldg[64];
    __shared__ int   sc[64];
    __shared__ int   lofs[64];
    const int tid  = threadIdx.x;
    const int base = bucketBase[blockIdx.x];
    const int end  = bucketBase[blockIdx.x + 1];

    if (tid < 64) { lh[tid] = 0; ldg[tid] = 0.f; }
    __syncthreads();
    for (int i = base + tid; i < end; i += 256) {
        int2 v = ebuf[i];
        int dl = ((unsigned)v.x) >> 26;
        atomicAdd(&lh[dl], 1);
        atomicAdd(&ldg[dl], __int_as_float(v.y));
    }
    __syncthreads();
    if (tid < 64) sc[tid] = lh[tid];
    __syncthreads();
    for (int off = 1; off < 64; off <<= 1) {
        int v = (tid < 64 && tid >= off) ? sc[tid - off] : 0;
        __syncthreads();
        if (tid < 64) sc[tid] += v;
        __syncthreads();
    }
    if (tid < 64) {
        int excl = sc[tid] - lh[tid];
        int d = (blockIdx.x << 6) + tid;
        if (d < N) {
            row[d]  = base + excl;
            dinv[d] = rsqrtf(fmaxf(1.0f + ldg[tid], 1e-12f));  // + self-loop
        }
        lofs[tid] = base + excl;
    }
    __syncthreads();
    for (int i = base + tid; i < end; i += 256) {
        int2 v = ebuf[i];
        unsigned u = (unsigned)v.x;
        int dl = u >> 26;
        int s  = u & 0x03FFFFFF;
        int p  = atomicAdd(&lofs[dl], 1);
        sn[p] = make_int2(s, v.y);
    }
    if (blockIdx.x == 0 && tid == 0) row[N] = E;
}

// payload.y <- w * dinv[src]
__global__ __launch_bounds__(256) void scale_pay(int2* __restrict__ sn,
                                                 const float* __restrict__ dinv,
                                                 int E) {
    int p = blockIdx.x * 256 + threadIdx.x;
    if (p < E) {
        int2 v = sn[p];
        sn[p] = make_int2(v.x, __float_as_int(__int_as_float(v.y) * dinv[v.x]));
    }
}

// ---------------- fused GCN aggregation (gather, no atomics) ---------
// out[i] = relu( (sum_e pay_e*t[src_e] + t[i]*dinv[i]) * dinv[i] + b )
__global__ __launch_bounds__(256) void gcn_agg(const float* __restrict__ t,
                                               const int2* __restrict__ sn,
                                               const int* __restrict__ row,
                                               const float* __restrict__ dinv,
                                               const float* __restrict__ bias,
                                               float* __restrict__ out, int N) {
    const int lane = threadIdx.x & 63;
    int i = __builtin_amdgcn_readfirstlane((int)(blockIdx.x * 4) + (threadIdx.x >> 6));
    if (i >= N) return;
    float di   = dinv[i];
    float self = t[(size_t)i * 64 + lane];
    float acc  = 0.f;
    int p  = row[i];
    int pe = row[i + 1];
    for (; p + 4 <= pe; p += 4) {
        int2 v0 = sn[p];
        int2 v1 = sn[p + 1];
        int2 v2 = sn[p + 2];
        int2 v3 = sn[p + 3];
        acc += t[(size_t)v0.x * 64 + lane] * __int_as_float(v0.y);
        acc += t[(size_t)v1.x * 64 + lane] * __int_as_float(v1.y);
        acc += t[(size_t)v2.x * 64 + lane] * __int_as_float(v2.y);
        acc += t[(size_t)v3.x * 64 + lane] * __int_as_float(v3.y);
    }
    for (; p < pe; ++p) {
        int2 v = sn[p];
        acc += t[(size_t)v.x * 64 + lane] * __int_as_float(v.y);
    }
    float x = (acc + self * di) * di + bias[lane];
    out[(size_t)i * 64 + lane] = fmaxf(x, 0.f);
}

// =====================================================================
extern "C" void kernel_launch(void* const* d_in, const int* in_sizes, int n_in,
                              void* d_out, int out_size, void* d_ws, size_t ws_size,
                              hipStream_t stream) {
    const float* x      = (const float*)d_in[0];
    const int*   ei     = (const int*)d_in[1];   // int32 per harness contract
    const float* ew     = (const float*)d_in[2];
    const float* enc1_w = (const float*)d_in[3];
    const float* enc1_b = (const float*)d_in[4];
    const float* enc2_w = (const float*)d_in[5];
    const float* enc2_b = (const float*)d_in[6];
    const float* gcn1_w = (const float*)d_in[7];
    const float* gcn1_b = (const float*)d_in[8];
    const float* gcn2_w = (const float*)d_in[9];
    const float* gcn2_b = (const float*)d_in[10];
    const float* dec1_w = (const float*)d_in[11];
    const float* dec1_b = (const float*)d_in[12];
    const float* dec2_w = (const float*)d_in[13];
    const float* dec2_b = (const float*)d_in[14];

    const int N  = in_sizes[0] / 256;    // 50000
    const int E  = in_sizes[2];          // 1600000
    const int NB = (N + 63) / 64;        // 782 buckets
    const int NCNT = NB * NBLK;          // 100096 counters
    const int NS   = (NCNT + 511) / 512; // 196 scan blocks

    // workspace (~40 MB):
    //  bufA [N*128 floats]: h1 -> { sn[E] int2 | ebuf[E] int2 (=bufC) } -> h5
    //  bufB [N*64]: h2/h3/h4 ; dinv[N]; row[N+1];
    //  cnt[NCNT]; pos[NCNT]; bucketBase[NB+1]; bs[256]
    float* ws   = (float*)d_ws;
    float* bufA = ws;
    int2*  sn   = (int2*)bufA;                  // E int2 (first half of bufA)
    float* bufC = bufA + (size_t)2 * E;         // N*64 floats (second half)
    int2*  ebuf = (int2*)bufC;                  // aliases bufC during build
    float* bufB = bufA + (size_t)N * 128;       // N*64
    float* dinv = bufB + (size_t)N * 64;        // N
    int*   row  = (int*)(dinv + N);             // N+1
    int*   cnt  = row + (N + 1);                // NCNT
    int*   pos  = cnt + NCNT;                   // NCNT
    int*   bucketBase = pos + NCNT;             // NB+1
    int*   bs   = bucketBase + (NB + 1);        // 256

    const int gemmGrid = (N + 127) / 128;       // 391
    const int nBlkE    = (E + 255) / 256;       // 6250

    // encoder
    gemm_mf<256, 128, 1, true><<<dim3(gemmGrid, 2), 256, 0, stream>>>(
        x, enc1_w, enc1_b, bufA, N);
    gemm_mf<128, 64, 1, true><<<dim3(gemmGrid, 1), 256, 0, stream>>>(
        bufA, enc2_w, enc2_b, bufB, N);

    // CSR build, zero global atomics (shared by both GCN layers)
    count_k<<<NBLK, 256, 0, stream>>>(ei, cnt, NB, E);
    scan1<<<NS, 256, 0, stream>>>(cnt, pos, bs, NCNT);
    scan_tops<<<1, 256, 0, stream>>>(bs, NS);
    scan2<<<NS, 256, 0, stream>>>(pos, bs, bucketBase, NCNT, NB, E);
    place_k<<<NBLK, 256, 0, stream>>>(ei, ew, pos, ebuf, NB, E);
    bucket_build<<<NB, 256, 0, stream>>>(ebuf, bucketBase, sn, row, dinv, N, E);
    scale_pay<<<nBlkE, 256, 0, stream>>>(sn, dinv, E);

    // GCN layer 1
    gemm_mf<64, 64, 0, false><<<dim3(gemmGrid, 1), 256, 0, stream>>>(
        bufB, gcn1_w, nullptr, bufC, N);
    gcn_agg<<<(N + 3) / 4, 256, 0, stream>>>(bufC, sn, row, dinv, gcn1_b, bufB, N);

    // GCN layer 2
    gemm_mf<64, 64, 0, false><<<dim3(gemmGrid, 1), 256, 0, stream>>>(
        bufB, gcn2_w, nullptr, bufC, N);
    gcn_agg<<<(N + 3) / 4, 256, 0, stream>>>(bufC, sn, row, dinv, gcn2_b, bufB, N);

    // decoder
    gemm_mf<64, 128, 1, true><<<dim3(gemmGrid, 2), 256, 0, stream>>>(
        bufB, dec1_w, dec1_b, bufA, N);
    gemm_mf<128, 256, 2, true><<<dim3(gemmGrid, 4), 256, 0, stream>>>(
        bufA, dec2_w, dec2_b, (float*)d_out, N);
}